// Round 11
// baseline (37468.637 us; speedup 1.0000x reference)
//
#include <hip/hip_runtime.h>
#include <math.h>

#define NB 8
#define NS 2048
#define NE 768
#define NU 1024
#define NBB 512
#define NH 3072
#define NBS (NB*NS)   // 16384
#define NWG 128

typedef float f32x4v __attribute__((ext_vector_type(4)));
typedef __bf16 bf16x8v __attribute__((ext_vector_type(8)));
typedef unsigned short u16x8v __attribute__((ext_vector_type(8)));
typedef unsigned short u16x4v __attribute__((ext_vector_type(4)));

__device__ __forceinline__ unsigned short f2bf(float f) {
  unsigned int u = __builtin_bit_cast(unsigned int, f);
  u = (u + 0x7fffu + ((u >> 16) & 1u)) >> 16;
  return (unsigned short)u;
}
__device__ __forceinline__ float bf2f(unsigned short h) {
  unsigned int u = ((unsigned int)h) << 16;
  return __builtin_bit_cast(float, u);
}

// agent-scope (device) relaxed ops: sc0 sc1 loads/stores, coherent at LLC.
__device__ __forceinline__ float ald(const float* p) {
  return __hip_atomic_load((const float*)p, __ATOMIC_RELAXED, __HIP_MEMORY_SCOPE_AGENT);
}
__device__ __forceinline__ void ast(float* p, float v) {
  __hip_atomic_store(p, v, __ATOMIC_RELAXED, __HIP_MEMORY_SCOPE_AGENT);
}
__device__ __forceinline__ unsigned aldu(const unsigned* p) {
  return __hip_atomic_load(p, __ATOMIC_RELAXED, __HIP_MEMORY_SCOPE_AGENT);
}
__device__ __forceinline__ void astu(unsigned* p, unsigned v) {
  __hip_atomic_store(p, v, __ATOMIC_RELAXED, __HIP_MEMORY_SCOPE_AGENT);
}
// acquire fence at agent scope: invalidates L1/L2 (buffer_inv) WITHOUT the
// writeback that made __threadfence catastrophic (r2). After this, NORMAL
// cached loads observe LLC-fresh data written by other blocks' sc stores.
__device__ __forceinline__ void acqf() {
  __builtin_amdgcn_fence(__ATOMIC_ACQUIRE, "agent");
}

// ---------------- leader barrier with PRIVATE release lines (r9-proven) -------
__device__ __forceinline__ void gbar5(unsigned* bar, int bx, unsigned tick) {
  __syncthreads();                          // drains this block's sc data stores
  int tid = threadIdx.x;
  if (bx == 0) {
    if (tid < 64) {
      if (tid == 0) astu(&bar[0], tick);    // leader's own arrival
      unsigned m;
      do {
        unsigned a = aldu(&bar[tid * 16]);
        unsigned b = aldu(&bar[(tid + 64) * 16]);
        m = a < b ? a : b;
        #pragma unroll
        for (int s = 1; s < 64; s <<= 1) {
          unsigned o = __shfl_xor(m, s);
          m = m < o ? m : o;
        }
      } while (m < tick);
      astu(&bar[2048 + tid * 16], tick);          // release broadcast
      astu(&bar[2048 + (tid + 64) * 16], tick);
    }
  } else {
    if (tid == 0) {
      astu(&bar[bx * 16], tick);            // arrival
      while (aldu(&bar[2048 + bx * 16]) < tick) {}  // hot spin, private line
    }
  }
  __syncthreads();
}

// ---------------- transpose kernels (weight prep) ----------------
__global__ __launch_bounds__(256) void tr_f32(const float* __restrict__ in,
                                              float* __restrict__ out, int R, int C) {
  __shared__ float tile[32][33];
  int c0 = blockIdx.x * 32, r0 = blockIdx.y * 32;
  int tx = threadIdx.x, ty = threadIdx.y;  // block (32,8)
  #pragma unroll
  for (int i = 0; i < 32; i += 8)
    tile[ty + i][tx] = in[(long)(r0 + ty + i) * C + c0 + tx];
  __syncthreads();
  #pragma unroll
  for (int i = 0; i < 32; i += 8)
    out[(long)(c0 + ty + i) * R + r0 + tx] = tile[tx][ty + i];
}

__global__ __launch_bounds__(256) void tr_f32_bf16(const float* __restrict__ in,
                                                   unsigned short* __restrict__ out, int R, int C) {
  __shared__ float tile[32][33];
  int c0 = blockIdx.x * 32, r0 = blockIdx.y * 32;
  int tx = threadIdx.x, ty = threadIdx.y;
  #pragma unroll
  for (int i = 0; i < 32; i += 8)
    tile[ty + i][tx] = in[(long)(r0 + ty + i) * C + c0 + tx];
  __syncthreads();
  #pragma unroll
  for (int i = 0; i < 32; i += 8)
    out[(long)(c0 + ty + i) * R + r0 + tx] = f2bf(tile[tx][ty + i]);
}

// transpose + split into bf16 hi/lo pair (for ~fp32-precision GEMM)
__global__ __launch_bounds__(256) void tr_f32_bf16split(const float* __restrict__ in,
    unsigned short* __restrict__ oh, unsigned short* __restrict__ ol, int R, int C) {
  __shared__ float tile[32][33];
  int c0 = blockIdx.x * 32, r0 = blockIdx.y * 32;
  int tx = threadIdx.x, ty = threadIdx.y;
  #pragma unroll
  for (int i = 0; i < 32; i += 8)
    tile[ty + i][tx] = in[(long)(r0 + ty + i) * C + c0 + tx];
  __syncthreads();
  #pragma unroll
  for (int i = 0; i < 32; i += 8) {
    float v = tile[tx][ty + i];
    unsigned short h = f2bf(v);
    long idx = (long)(c0 + ty + i) * R + r0 + tx;
    oh[idx] = h;
    ol[idx] = f2bf(v - bf2f(h));
  }
}

// ---------------- LayerNorm (one wave per row of 768) -> bf16 hi/lo out ----------------
__global__ __launch_bounds__(256) void ln_kernel(const float* __restrict__ in,
    const float* __restrict__ gw, const float* __restrict__ bw,
    unsigned short* __restrict__ outh, unsigned short* __restrict__ outl) {
  int lane = threadIdx.x & 63;
  long row = (long)blockIdx.x * 4 + (threadIdx.x >> 6);
  const float4* rp = (const float4*)(in + row * NE);
  float4 v[3];
  float s = 0.f, sq = 0.f;
  #pragma unroll
  for (int j = 0; j < 3; ++j) {
    v[j] = rp[lane + j * 64];
    s += v[j].x + v[j].y + v[j].z + v[j].w;
    sq += v[j].x*v[j].x + v[j].y*v[j].y + v[j].z*v[j].z + v[j].w*v[j].w;
  }
  #pragma unroll
  for (int m = 1; m < 64; m <<= 1) { s += __shfl_xor(s, m); sq += __shfl_xor(sq, m); }
  float mu = s * (1.f / NE);
  float rs = rsqrtf(sq * (1.f / NE) - mu * mu + 1e-5f);
  #pragma unroll
  for (int j = 0; j < 3; ++j) {
    int c4 = lane + j * 64;
    float4 g4 = ((const float4*)gw)[c4];
    float4 b4 = ((const float4*)bw)[c4];
    float f0 = (v[j].x - mu) * rs * g4.x + b4.x;
    float f1 = (v[j].y - mu) * rs * g4.y + b4.y;
    float f2 = (v[j].z - mu) * rs * g4.z + b4.z;
    float f3 = (v[j].w - mu) * rs * g4.w + b4.w;
    u16x4v oh, ol;
    oh[0] = f2bf(f0); ol[0] = f2bf(f0 - bf2f(oh[0]));
    oh[1] = f2bf(f1); ol[1] = f2bf(f1 - bf2f(oh[1]));
    oh[2] = f2bf(f2); ol[2] = f2bf(f2 - bf2f(oh[2]));
    oh[3] = f2bf(f3); ol[3] = f2bf(f3 - bf2f(oh[3]));
    *(u16x4v*)(outh + row * NE + (long)c4 * 4) = oh;
    *(u16x4v*)(outl + row * NE + (long)c4 * 4) = ol;
  }
}

// ---------------- bf16 MFMA GEMM: C[M,N] = A[M,K] @ Bt[N,K]^T (+bias, epilogue) ---
// EPI 0: Cf = acc + bias            (fp32 out)
// EPI 1: Cb = bf16(gelu(acc+bias))  (bf16 out)
// EPI 2: Cf = acc + bias + res      (fp32 out, residual add; res may alias Cf)
// EPI 3: Cf += acc                  (fp32 accumulate, no bias)
template<int EPI>
__global__ __launch_bounds__(256) void gemm_bf16(
    const unsigned short* __restrict__ A, const unsigned short* __restrict__ Bt,
    const float* __restrict__ bias, const float* res,
    float* Cf, unsigned short* Cb, int M, int N, int K)
{
  __shared__ unsigned short lA[128][72];
  __shared__ unsigned short lB[128][72];
  int tid = threadIdx.x;
  int lane = tid & 63, wave = tid >> 6;
  int wr = wave >> 1, wc = wave & 1;
  int r15 = lane & 15, hi = lane >> 4;
  int ntn = N >> 7;
  long m0 = (long)(blockIdx.x / ntn) << 7;
  long n0 = (long)(blockIdx.x % ntn) << 7;
  f32x4v acc[4][4];
  #pragma unroll
  for (int m = 0; m < 4; ++m)
    #pragma unroll
    for (int n = 0; n < 4; ++n) acc[m][n] = (f32x4v){0.f, 0.f, 0.f, 0.f};

  for (int kt = 0; kt < K; kt += 64) {
    u16x8v ra[4], rb[4];
    #pragma unroll
    for (int i = 0; i < 4; ++i) {
      int c = tid + (i << 8);
      int rw = c >> 3, ko = (c & 7) << 3;
      ra[i] = *(const u16x8v*)(A + (m0 + rw) * K + kt + ko);
      rb[i] = *(const u16x8v*)(Bt + (n0 + rw) * K + kt + ko);
    }
    __syncthreads();
    #pragma unroll
    for (int i = 0; i < 4; ++i) {
      int c = tid + (i << 8);
      int rw = c >> 3, ko = (c & 7) << 3;
      *(u16x8v*)(&lA[rw][ko]) = ra[i];
      *(u16x8v*)(&lB[rw][ko]) = rb[i];
    }
    __syncthreads();
    #pragma unroll
    for (int ks = 0; ks < 64; ks += 32) {
      bf16x8v af[4], bfr[4];
      #pragma unroll
      for (int m = 0; m < 4; ++m)
        af[m] = *(const bf16x8v*)(&lA[wr * 64 + m * 16 + r15][ks + hi * 8]);
      #pragma unroll
      for (int n = 0; n < 4; ++n)
        bfr[n] = *(const bf16x8v*)(&lB[wc * 64 + n * 16 + r15][ks + hi * 8]);
      #pragma unroll
      for (int m = 0; m < 4; ++m)
        #pragma unroll
        for (int n = 0; n < 4; ++n)
          acc[m][n] = __builtin_amdgcn_mfma_f32_16x16x32_bf16(af[m], bfr[n], acc[m][n], 0, 0, 0);
    }
  }
  #pragma unroll
  for (int m = 0; m < 4; ++m) {
    long rbase = m0 + wr * 64 + m * 16 + hi * 4;
    #pragma unroll
    for (int n = 0; n < 4; ++n) {
      long cg = n0 + wc * 64 + n * 16 + r15;
      float bs = (EPI == 3) ? 0.f : bias[cg];
      #pragma unroll
      for (int e = 0; e < 4; ++e) {
        long row = rbase + e;
        float vv = acc[m][n][e] + bs;
        if (EPI == 0) {
          Cf[row * N + cg] = vv;
        } else if (EPI == 1) {
          float gl = 0.5f * vv * (1.f + erff(vv * 0.70710678118f));
          Cb[row * N + cg] = f2bf(gl);
        } else if (EPI == 2) {
          Cf[row * N + cg] = vv + res[row * N + cg];
        } else {
          Cf[row * N + cg] += vv;
        }
      }
    }
  }
}

// ---------------- persistent scan kernel: CACHED EXCHANGE READS --------------
// 128 WGs x 256 thr; 2 gbar5 barriers per timestep.
// Exchange protocol: producers write h/bb/cfc via agent-scope sc stores
// (write-through to LLC, L2 never dirty for these lines). After each barrier
// release, every thread runs an agent-ACQUIRE fence (buffer_inv: invalidate
// only, no writeback) and then stages with NORMAL cached float4 loads —
// first touch fills 64B lines from LLC, the 16 blocks per XCD share them in
// L2. This removes the ~786K 8B sc-load LLC transactions per step that all
// prior sync variants paid (the invariant ~10.5us/step floor).
__global__ __launch_bounds__(256) void scan_kernel(
    const float* __restrict__ pre, const float* __restrict__ WhhT,
    const float* __restrict__ WhT,
    const float* __restrict__ bf1, const float* __restrict__ bf2,
    const float* __restrict__ bta, const float* __restrict__ btb,
    const float* __restrict__ hx,
    float* hbuf, float* bbf, float* __restrict__ cfc, unsigned* bar)
{
  __shared__ float lsd[NB * NU];            // h staging (32KB); bb reuses first 16KB
  __shared__ float4 lpre[512];              // pre cache: [b][t&63] -> 4 j's (8KB)
  __shared__ float lpart[4][4][2][8];
  int tid = threadIdx.x;
  int lane = tid & 63, wave = tid >> 6;
  int bx = blockIdx.x;
  int j1 = (bx << 2) + wave;
  int head = lane >> 4, v2 = (lane >> 3) & 1, jsub = lane & 7;
  int vg = (bx << 3) + (wave << 1) + v2;
  const float4* W14 = (const float4*)(WhhT + (long)j1 * NU);
  const float4* W24 = (const float4*)(WhT + ((long)head * NU + vg) * NBB);
  const float4* ls4 = (const float4*)lsd;
  float4* ls4w = (float4*)lsd;
  const float4* hb4 = (const float4*)hbuf;
  const float4* bb4 = (const float4*)bbf;
  const float* lpf = (const float*)lpre;
  unsigned tick = 0;

  // hoist this wave's Whh row (4KB across 64 lanes -> 4 float4/lane)
  float4 wreg[4];
  #pragma unroll
  for (int c = 0; c < 4; ++c) wreg[c] = W14[(c << 6) + lane];
  // hoist stage-2 weight rows (16 float4/lane = 64 VGPR)
  float4 w2reg[16];
  #pragma unroll
  for (int c = 0; c < 16; ++c) w2reg[c] = W24[(c << 3) + jsub];

  // tail-update constants
  int vl = tid >> 3, bq = tid & 7;
  int wv = vl >> 1, qq = vl & 1;
  int vo = (bx << 3) + vl;
  float cb1 = 0.f, cb2 = 0.f, cbt = 0.f;
  if (tid < 64) { cb1 = bf1[vo]; cb2 = bf2[vo]; cbt = bta[vo] + btb[vo]; }

  // init h state (sc-stores -> LLC)
  if (tid < 64) ast(&hbuf[(bx << 6) + tid], hx[(bx << 6) + tid]);
  gbar5(bar, bx, ++tick);
  acqf();

  for (int t = 0; t < NS; ++t) {
    // ---- bulk pre reload every 64 steps (normal coalesced loads) ----
    if ((t & 63) == 0) {
      #pragma unroll
      for (int i = 0; i < 2; ++i) {
        int idx = (i << 8) + tid;              // 0..511
        int b = idx >> 6, tq = idx & 63;
        lpre[idx] = *(const float4*)(pre + ((long)b * NS + t + tq) * NBB + (bx << 2));
      }
    }
    // ---- stage h into LDS: NORMAL cached float4 loads (L2-shared per XCD) ----
    {
      float4 rv[8];
      #pragma unroll
      for (int i = 0; i < 8; ++i) rv[i] = hb4[(i << 8) + tid];
      #pragma unroll
      for (int i = 0; i < 8; ++i) ls4w[(i << 8) + tid] = rv[i];
    }
    __syncthreads();

    // ---- stage 1: bb = lecun_tanh(pre + h @ W_hh) ----
    float a1[8];
    #pragma unroll
    for (int b = 0; b < 8; ++b) a1[b] = 0.f;
    #pragma unroll
    for (int c = 0; c < 4; ++c) {
      int idx = (c << 6) + lane;
      float4 w = wreg[c];
      #pragma unroll
      for (int b = 0; b < 8; ++b) {
        float4 hv = ls4[(b << 8) + idx];
        a1[b] += w.x * hv.x + w.y * hv.y + w.z * hv.z + w.w * hv.w;
      }
    }
    #pragma unroll
    for (int m = 1; m < 64; m <<= 1)
      #pragma unroll
      for (int b = 0; b < 8; ++b) a1[b] += __shfl_xor(a1[b], m);
    if (lane == 0) {
      int tq = t & 63;
      #pragma unroll
      for (int b = 0; b < 8; ++b) {
        float s = a1[b] + lpf[(((b << 6) | tq) << 2) + wave];
        ast(&bbf[b * NBB + j1], 1.7159f * tanhf(0.666f * s));
      }
    }
    gbar5(bar, bx, ++tick);
    acqf();

    // ---- stage bb into LDS: NORMAL cached float4 loads ----
    {
      float4 rv[4];
      #pragma unroll
      for (int i = 0; i < 4; ++i) rv[i] = bb4[(i << 8) + tid];
      #pragma unroll
      for (int i = 0; i < 4; ++i) ls4w[(i << 8) + tid] = rv[i];
    }
    __syncthreads();

    // ---- stage 2: heads + h update ----
    float a2[8];
    #pragma unroll
    for (int b = 0; b < 8; ++b) a2[b] = 0.f;
    #pragma unroll
    for (int c = 0; c < 16; ++c) {
      int idx = (c << 3) + jsub;
      float4 w = w2reg[c];
      #pragma unroll
      for (int b = 0; b < 8; ++b) {
        float4 bv = ls4[(b << 7) + idx];
        a2[b] += w.x * bv.x + w.y * bv.y + w.z * bv.z + w.w * bv.w;
      }
    }
    #pragma unroll
    for (int m = 1; m < 8; m <<= 1)
      #pragma unroll
      for (int b = 0; b < 8; ++b) a2[b] += __shfl_xor(a2[b], m);
    if (jsub == 0) {
      #pragma unroll
      for (int b = 0; b < 8; ++b) lpart[wave][head][v2][b] = a2[b];
    }
    __syncthreads();
    float hn = 0.f;
    if (tid < 64) {
      float d1 = lpart[wv][0][qq][bq] + cb1;
      float d2 = lpart[wv][1][qq][bq] + cb2;
      float dt = lpart[wv][2][qq][bq] + lpart[wv][3][qq][bq] + cbt;
      float f1 = 1.7159f * tanhf(0.666f * d1);
      float f2 = 1.7159f * tanhf(0.666f * d2);
      float ti = 1.f / (1.f + expf(-dt));
      hn = f1 * (1.f - ti) + ti * f2;
      ast(&hbuf[bq * NU + vo], hn);
    }
    gbar5(bar, bx, ++tick);
    acqf();
    // cfc store AFTER the barrier (sc store: write-through, no dirty L2 line
    // for the acquire-invalidate to interact with); drain overlaps next step
    if (tid < 64 && vo < NE) ast(&cfc[((long)bq * NS + t) * NE + vo], hn);
  }
}

// ---------------- LIF gate + residual (writes x1 into d_out), copy hx ----------------
__global__ __launch_bounds__(256) void lif_kernel(
    const float* __restrict__ x, const float* __restrict__ cfc,
    const float* __restrict__ thr, const float* __restrict__ leak,
    const float* __restrict__ steep, const float* __restrict__ hbuf,
    float* __restrict__ x1, float* __restrict__ outTail)
{
  long i4 = (long)blockIdx.x * blockDim.x + threadIdx.x;  // float4 index
  float4 xv = ((const float4*)x)[i4];
  float4 cv;
  {
    const float* cp = cfc + (i4 << 2);
    cv.x = ald(cp); cv.y = ald(cp + 1); cv.z = ald(cp + 2); cv.w = ald(cp + 3);
  }
  int col = (int)((i4 << 2) % NE);
  float4 tv = *(const float4*)(thr + col);
  float4 lv = *(const float4*)(leak + col);
  float4 sv = *(const float4*)(steep + col);
  float4 r;
#define LIF1(comp) { \
    float th = fabsf(tv.comp) * 0.1f; \
    float ls = 1.f / (1.f + expf(-lv.comp)); \
    float sp = (sv.comp > 20.f) ? sv.comp : log1pf(expf(sv.comp)); \
    float fire = 1.f / (1.f + expf(-sp * (fabsf(cv.comp) - th))); \
    float gate = fire + ls * (1.f - fire); \
    r.comp = xv.comp + cv.comp * gate; }
  LIF1(x) LIF1(y) LIF1(z) LIF1(w)
#undef LIF1
  ((float4*)x1)[i4] = r;
  if (i4 < (NB * NU / 4)) {
    // hbuf was written with sc stores; read it back with sc loads
    const float* hp = hbuf + (i4 << 2);
    float4 hv; hv.x = ald(hp); hv.y = ald(hp + 1); hv.z = ald(hp + 2); hv.w = ald(hp + 3);
    ((float4*)outTail)[i4] = hv;
  }
}

// ---------------- launch ----------------
extern "C" void kernel_launch(void* const* d_in, const int* in_sizes, int n_in,
                              void* d_out, int out_size, void* d_ws, size_t ws_size,
                              hipStream_t stream) {
  (void)in_sizes; (void)n_in; (void)out_size; (void)ws_size;
  const float* x     = (const float*)d_in[0];
  const float* hx    = (const float*)d_in[1];
  const float* ln1g  = (const float*)d_in[2];
  const float* ln1b  = (const float*)d_in[3];
  const float* ln2g  = (const float*)d_in[4];
  const float* ln2b  = (const float*)d_in[5];
  const float* Wbb   = (const float*)d_in[6];
  const float* bbb   = (const float*)d_in[7];
  const float* Wff1  = (const float*)d_in[8];
  const float* bff1  = (const float*)d_in[9];
  const float* Wff2  = (const float*)d_in[10];
  const float* bff2  = (const float*)d_in[11];
  const float* Wta   = (const float*)d_in[12];
  const float* btaP  = (const float*)d_in[13];
  const float* Wtb   = (const float*)d_in[14];
  const float* btbP  = (const float*)d_in[15];
  const float* lthr  = (const float*)d_in[16];
  const float* lleak = (const float*)d_in[17];
  const float* lstp  = (const float*)d_in[18];
  const float* W1    = (const float*)d_in[19];
  const float* b1    = (const float*)d_in[20];
  const float* W2    = (const float*)d_in[21];
  const float* b2    = (const float*)d_in[22];

  char* base = (char*)d_ws;
  unsigned short* normedH = (unsigned short*)base;                   // [0, 25165824)
  float* pre   = (float*)(base + 25165824);                          // [25165824, 58720256)
  float* cfc   = (float*)(base + 58720256);                          // [58720256, 109051904)
  unsigned short* gelu = (unsigned short*)base;                      // [0, 100663296) after cfc consumed
  unsigned short* normedL = (unsigned short*)(base + 109051904);     // [109051904, 134217728)
  unsigned short* h2      = (unsigned short*)(base + 109051904);     // same slot, later phase
  // barrier region: 16KB inside the normedL/h2 slot (dead during the scan;
  // h2 is written only after the scan completes)
  unsigned* bar = (unsigned*)(base + 125829120);                     // 16384 B
  unsigned short* wtbbH = (unsigned short*)(base + 134217728);       // 786432
  float* whhT  = (float*)(base + 135004160);                         // 2097152
  float* whT   = (float*)(base + 137101312);                         // 8388608
  unsigned short* w1t = (unsigned short*)(base + 145489920);         // 4718592
  unsigned short* w2t = (unsigned short*)(base + 150208512);         // 4718592
  float* hbuf  = (float*)(base + 154927104);                         // 32768
  float* bbf   = (float*)(base + 154959872);                         // 16384
  unsigned short* wtbbL = (unsigned short*)(base + 154980352);       // 786432 -> end 155766784
  float* xout  = (float*)d_out;
  float* outTail = xout + (size_t)NBS * NE;
  unsigned short* lnlo_dummy = (unsigned short*)base;                // scratch, overwritten by gelu

  dim3 b328(32, 8);
  // weight prep (transposed, K-contiguous layouts)
  tr_f32_bf16split<<<dim3(512/32, 768/32), b328, 0, stream>>>(Wbb, wtbbH, wtbbL, 768, 512);
  tr_f32<<<dim3(512/32, 1024/32), b328, 0, stream>>>(Wbb + 768*512, whhT, 1024, 512);
  tr_f32<<<dim3(1024/32, 512/32), b328, 0, stream>>>(Wff1, whT + 0*(size_t)NU*NBB, 512, 1024);
  tr_f32<<<dim3(1024/32, 512/32), b328, 0, stream>>>(Wff2, whT + 1*(size_t)NU*NBB, 512, 1024);
  tr_f32<<<dim3(1024/32, 512/32), b328, 0, stream>>>(Wta,  whT + 2*(size_t)NU*NBB, 512, 1024);
  tr_f32<<<dim3(1024/32, 512/32), b328, 0, stream>>>(Wtb,  whT + 3*(size_t)NU*NBB, 512, 1024);
  tr_f32_bf16<<<dim3(3072/32, 768/32), b328, 0, stream>>>(W1, w1t, 768, 3072);
  tr_f32_bf16<<<dim3(768/32, 3072/32), b328, 0, stream>>>(W2, w2t, 3072, 768);

  // LN1 (hi/lo split) + input-projection precompute in ~fp32 precision:
  // pre = nH@wH + nH@wL + nL@wH + b_bb
  ln_kernel<<<NBS/4, 256, 0, stream>>>(x, ln1g, ln1b, normedH, normedL);
  gemm_bf16<0><<<(NBS/128)*(NBB/128), 256, 0, stream>>>(normedH, wtbbH, bbb, nullptr,
                                                        pre, nullptr, NBS, NBB, NE);
  gemm_bf16<3><<<(NBS/128)*(NBB/128), 256, 0, stream>>>(normedH, wtbbL, bbb, nullptr,
                                                        pre, nullptr, NBS, NBB, NE);
  gemm_bf16<3><<<(NBS/128)*(NBB/128), 256, 0, stream>>>(normedL, wtbbH, bbb, nullptr,
                                                        pre, nullptr, NBS, NBB, NE);

  // zero the barrier region (stream-ordered after the pre-GEMMs that read
  // normedL, which this region aliases)
  hipMemsetAsync(bar, 0, 16384, stream);

  scan_kernel<<<NWG, 256, 0, stream>>>(pre, whhT, whT, bff1, bff2, btaP, btbP, hx,
                                       hbuf, bbf, cfc, bar);

  // LIF gate + residual -> x1 (stored in d_out), plus new_hx copy to output tail
  lif_kernel<<<(NBS*NE/4)/256, 256, 0, stream>>>(x, cfc, lthr, lleak, lstp, hbuf, xout, outTail);
  // LN2 + MLP with fused GELU and residual
  ln_kernel<<<NBS/4, 256, 0, stream>>>(xout, ln2g, ln2b, h2, lnlo_dummy);
  gemm_bf16<1><<<(NBS/128)*(NH/128), 256, 0, stream>>>(h2, w1t, b1, nullptr,
                                                       nullptr, gelu, NBS, NH, NE);
  gemm_bf16<2><<<(NBS/128)*(NE/128), 256, 0, stream>>>(gelu, w2t, b2, xout,
                                                       xout, nullptr, NBS, NE, NH);
}

// Round 12
// 18740.439 us; speedup vs baseline: 1.9993x; 1.9993x over previous
//
#include <hip/hip_runtime.h>
#include <math.h>

#define NB 8
#define NS 2048
#define NE 768
#define NU 1024
#define NBB 512
#define NH 3072
#define NBS (NB*NS)   // 16384

typedef float f32x4v __attribute__((ext_vector_type(4)));
typedef __bf16 bf16x8v __attribute__((ext_vector_type(8)));
typedef unsigned short u16x8v __attribute__((ext_vector_type(8)));
typedef unsigned short u16x4v __attribute__((ext_vector_type(4)));

__device__ __forceinline__ unsigned short f2bf(float f) {
  unsigned int u = __builtin_bit_cast(unsigned int, f);
  u = (u + 0x7fffu + ((u >> 16) & 1u)) >> 16;
  return (unsigned short)u;
}
__device__ __forceinline__ float bf2f(unsigned short h) {
  unsigned int u = ((unsigned int)h) << 16;
  return __builtin_bit_cast(float, u);
}

// agent-scope (device) relaxed ops: sc0 sc1 loads/stores, coherent at LLC.
__device__ __forceinline__ float ald(const float* p) {
  return __hip_atomic_load((const float*)p, __ATOMIC_RELAXED, __HIP_MEMORY_SCOPE_AGENT);
}
__device__ __forceinline__ void ast(float* p, float v) {
  __hip_atomic_store(p, v, __ATOMIC_RELAXED, __HIP_MEMORY_SCOPE_AGENT);
}
__device__ __forceinline__ float2 ald2(const float* p) {
  unsigned long long v = __hip_atomic_load((const unsigned long long*)p,
                             __ATOMIC_RELAXED, __HIP_MEMORY_SCOPE_AGENT);
  return __builtin_bit_cast(float2, v);
}
__device__ __forceinline__ unsigned aldu(const unsigned* p) {
  return __hip_atomic_load(p, __ATOMIC_RELAXED, __HIP_MEMORY_SCOPE_AGENT);
}
__device__ __forceinline__ void astu(unsigned* p, unsigned v) {
  __hip_atomic_store(p, v, __ATOMIC_RELAXED, __HIP_MEMORY_SCOPE_AGENT);
}

// ---------------- transpose kernels (weight prep) ----------------
__global__ __launch_bounds__(256) void tr_f32(const float* __restrict__ in,
                                              float* __restrict__ out, int R, int C) {
  __shared__ float tile[32][33];
  int c0 = blockIdx.x * 32, r0 = blockIdx.y * 32;
  int tx = threadIdx.x, ty = threadIdx.y;  // block (32,8)
  #pragma unroll
  for (int i = 0; i < 32; i += 8)
    tile[ty + i][tx] = in[(long)(r0 + ty + i) * C + c0 + tx];
  __syncthreads();
  #pragma unroll
  for (int i = 0; i < 32; i += 8)
    out[(long)(c0 + ty + i) * R + r0 + tx] = tile[tx][ty + i];
}

__global__ __launch_bounds__(256) void tr_f32_bf16(const float* __restrict__ in,
                                                   unsigned short* __restrict__ out, int R, int C) {
  __shared__ float tile[32][33];
  int c0 = blockIdx.x * 32, r0 = blockIdx.y * 32;
  int tx = threadIdx.x, ty = threadIdx.y;
  #pragma unroll
  for (int i = 0; i < 32; i += 8)
    tile[ty + i][tx] = in[(long)(r0 + ty + i) * C + c0 + tx];
  __syncthreads();
  #pragma unroll
  for (int i = 0; i < 32; i += 8)
    out[(long)(c0 + ty + i) * R + r0 + tx] = f2bf(tile[tx][ty + i]);
}

// transpose + split into bf16 hi/lo pair (for ~fp32-precision GEMM)
__global__ __launch_bounds__(256) void tr_f32_bf16split(const float* __restrict__ in,
    unsigned short* __restrict__ oh, unsigned short* __restrict__ ol, int R, int C) {
  __shared__ float tile[32][33];
  int c0 = blockIdx.x * 32, r0 = blockIdx.y * 32;
  int tx = threadIdx.x, ty = threadIdx.y;
  #pragma unroll
  for (int i = 0; i < 32; i += 8)
    tile[ty + i][tx] = in[(long)(r0 + ty + i) * C + c0 + tx];
  __syncthreads();
  #pragma unroll
  for (int i = 0; i < 32; i += 8) {
    float v = tile[tx][ty + i];
    unsigned short h = f2bf(v);
    long idx = (long)(c0 + ty + i) * R + r0 + tx;
    oh[idx] = h;
    ol[idx] = f2bf(v - bf2f(h));
  }
}

// ---------------- LayerNorm (one wave per row of 768) -> bf16 hi/lo out ----------------
__global__ __launch_bounds__(256) void ln_kernel(const float* __restrict__ in,
    const float* __restrict__ gw, const float* __restrict__ bw,
    unsigned short* __restrict__ outh, unsigned short* __restrict__ outl) {
  int lane = threadIdx.x & 63;
  long row = (long)blockIdx.x * 4 + (threadIdx.x >> 6);
  const float4* rp = (const float4*)(in + row * NE);
  float4 v[3];
  float s = 0.f, sq = 0.f;
  #pragma unroll
  for (int j = 0; j < 3; ++j) {
    v[j] = rp[lane + j * 64];
    s += v[j].x + v[j].y + v[j].z + v[j].w;
    sq += v[j].x*v[j].x + v[j].y*v[j].y + v[j].z*v[j].z + v[j].w*v[j].w;
  }
  #pragma unroll
  for (int m = 1; m < 64; m <<= 1) { s += __shfl_xor(s, m); sq += __shfl_xor(sq, m); }
  float mu = s * (1.f / NE);
  float rs = rsqrtf(sq * (1.f / NE) - mu * mu + 1e-5f);
  #pragma unroll
  for (int j = 0; j < 3; ++j) {
    int c4 = lane + j * 64;
    float4 g4 = ((const float4*)gw)[c4];
    float4 b4 = ((const float4*)bw)[c4];
    float f0 = (v[j].x - mu) * rs * g4.x + b4.x;
    float f1 = (v[j].y - mu) * rs * g4.y + b4.y;
    float f2 = (v[j].z - mu) * rs * g4.z + b4.z;
    float f3 = (v[j].w - mu) * rs * g4.w + b4.w;
    u16x4v oh, ol;
    oh[0] = f2bf(f0); ol[0] = f2bf(f0 - bf2f(oh[0]));
    oh[1] = f2bf(f1); ol[1] = f2bf(f1 - bf2f(oh[1]));
    oh[2] = f2bf(f2); ol[2] = f2bf(f2 - bf2f(oh[2]));
    oh[3] = f2bf(f3); ol[3] = f2bf(f3 - bf2f(oh[3]));
    *(u16x4v*)(outh + row * NE + (long)c4 * 4) = oh;
    *(u16x4v*)(outl + row * NE + (long)c4 * 4) = ol;
  }
}

// ---------------- bf16 MFMA GEMM: C[M,N] = A[M,K] @ Bt[N,K]^T (+bias, epilogue) ---
// EPI 0: Cf = acc + bias            (fp32 out)
// EPI 1: Cb = bf16(gelu(acc+bias))  (bf16 out)
// EPI 2: Cf = acc + bias + res      (fp32 out, residual add; res may alias Cf)
// EPI 3: Cf += acc                  (fp32 accumulate, no bias)
template<int EPI>
__global__ __launch_bounds__(256) void gemm_bf16(
    const unsigned short* __restrict__ A, const unsigned short* __restrict__ Bt,
    const float* __restrict__ bias, const float* res,
    float* Cf, unsigned short* Cb, int M, int N, int K)
{
  __shared__ unsigned short lA[128][72];
  __shared__ unsigned short lB[128][72];
  int tid = threadIdx.x;
  int lane = tid & 63, wave = tid >> 6;
  int wr = wave >> 1, wc = wave & 1;
  int r15 = lane & 15, hi = lane >> 4;
  int ntn = N >> 7;
  long m0 = (long)(blockIdx.x / ntn) << 7;
  long n0 = (long)(blockIdx.x % ntn) << 7;
  f32x4v acc[4][4];
  #pragma unroll
  for (int m = 0; m < 4; ++m)
    #pragma unroll
    for (int n = 0; n < 4; ++n) acc[m][n] = (f32x4v){0.f, 0.f, 0.f, 0.f};

  for (int kt = 0; kt < K; kt += 64) {
    u16x8v ra[4], rb[4];
    #pragma unroll
    for (int i = 0; i < 4; ++i) {
      int c = tid + (i << 8);
      int rw = c >> 3, ko = (c & 7) << 3;
      ra[i] = *(const u16x8v*)(A + (m0 + rw) * K + kt + ko);
      rb[i] = *(const u16x8v*)(Bt + (n0 + rw) * K + kt + ko);
    }
    __syncthreads();
    #pragma unroll
    for (int i = 0; i < 4; ++i) {
      int c = tid + (i << 8);
      int rw = c >> 3, ko = (c & 7) << 3;
      *(u16x8v*)(&lA[rw][ko]) = ra[i];
      *(u16x8v*)(&lB[rw][ko]) = rb[i];
    }
    __syncthreads();
    #pragma unroll
    for (int ks = 0; ks < 64; ks += 32) {
      bf16x8v af[4], bfr[4];
      #pragma unroll
      for (int m = 0; m < 4; ++m)
        af[m] = *(const bf16x8v*)(&lA[wr * 64 + m * 16 + r15][ks + hi * 8]);
      #pragma unroll
      for (int n = 0; n < 4; ++n)
        bfr[n] = *(const bf16x8v*)(&lB[wc * 64 + n * 16 + r15][ks + hi * 8]);
      #pragma unroll
      for (int m = 0; m < 4; ++m)
        #pragma unroll
        for (int n = 0; n < 4; ++n)
          acc[m][n] = __builtin_amdgcn_mfma_f32_16x16x32_bf16(af[m], bfr[n], acc[m][n], 0, 0, 0);
    }
  }
  #pragma unroll
  for (int m = 0; m < 4; ++m) {
    long rbase = m0 + wr * 64 + m * 16 + hi * 4;
    #pragma unroll
    for (int n = 0; n < 4; ++n) {
      long cg = n0 + wc * 64 + n * 16 + r15;
      float bs = (EPI == 3) ? 0.f : bias[cg];
      #pragma unroll
      for (int e = 0; e < 4; ++e) {
        long row = rbase + e;
        float vv = acc[m][n][e] + bs;
        if (EPI == 0) {
          Cf[row * N + cg] = vv;
        } else if (EPI == 1) {
          float gl = 0.5f * vv * (1.f + erff(vv * 0.70710678118f));
          Cb[row * N + cg] = f2bf(gl);
        } else if (EPI == 2) {
          Cf[row * N + cg] = vv + res[row * N + cg];
        } else {
          Cf[row * N + cg] += vv;
        }
      }
    }
  }
}

// ------------- persistent scan: PRODUCER/CONSUMER SPECIALIZED BLOCKS ----------
// grid = 128 x 512 threads, NO grid barrier.
//   bx <  64: J-block jb — owns j = jb*8..+7. waits doneV(row jb) >= t+1,
//             stages h(t) (32KB sc loads), stage-1 dot, writes bb slice (sc),
//             then signals doneJ[consumer][jb] = t+1 (64 private cells).
//   bx >= 64: V-block vb — owns v = vb*16..+15. waits doneJ(row vb) >= t+1,
//             stages bb(t) (16KB), stage-2 + h update, writes h(t+1) (sc),
//             signals doneV[consumer][vb] = t+2; cfc store off critical path.
// done matrices: (consumer,producer)-private 64B cells — no shared poll lines,
// no leader, no release broadcast. Handshake = drain + done RT + catch RT.
// WAR safety: doneJ=t+1 is ordered (vmcnt) after J's bb stores AND h loads, so
// V seeing all doneJ>=t+1 may overwrite h; symmetric for bb. Strict
// alternation => no deadlock; monotonic ticks; matrices zeroed per launch.
__global__ __launch_bounds__(512) void scan_kernel(
    const float* __restrict__ pre, const float* __restrict__ WhhT,
    const float* __restrict__ WhT,
    const float* __restrict__ bf1, const float* __restrict__ bf2,
    const float* __restrict__ bta, const float* __restrict__ btb,
    const float* __restrict__ hx,
    float* hbuf, float* bbf, float* __restrict__ cfc,
    unsigned* doneV, unsigned* doneJ)
{
  __shared__ float lsd[NB * NU];            // J: h image 32KB / V: bb image 16KB
  __shared__ float lpre[4096];              // J only: [b][t&63][8 j] = 16KB
  __shared__ float lpart[8][4][2][8];       // V only: 2KB
  int tid = threadIdx.x;
  int lane = tid & 63, wave = tid >> 6;     // 8 waves
  int bx = blockIdx.x;
  const float4* ls4 = (const float4*)lsd;
  float2* ls2 = (float2*)lsd;

  if (bx < 64) {
    // ================= J-block =================
    int jb = bx;
    int j1 = (jb << 3) + wave;              // this wave's j unit
    const float4* W14 = (const float4*)(WhhT + (long)j1 * NU);
    float4 wreg[4];
    #pragma unroll
    for (int c = 0; c < 4; ++c) wreg[c] = W14[(c << 6) + lane];
    const unsigned* mycell = doneV + ((jb << 10) + (lane << 4));

    for (int t = 0; t < NS; ++t) {
      // bulk pre reload every 64 steps (normal loads; in flight during poll)
      if ((t & 63) == 0) {
        int b = tid >> 6, tq = tid & 63;
        const float* src = pre + ((long)b * NS + t + tq) * NBB + (jb << 3);
        float4 p0 = *(const float4*)src;
        float4 p1 = *(const float4*)(src + 4);
        *(float4*)(&lpre[tid * 8])     = p0;
        *(float4*)(&lpre[tid * 8 + 4]) = p1;
      }
      // wait: h(t) ready (64 private cells, one per producer V-block)
      if (wave == 0) {
        while (aldu(mycell) < (unsigned)(t + 1)) {}
      }
      __syncthreads();
      // stage h(t): 32KB via 8B sc loads (512 thr x 8)
      {
        float2 rv[8];
        #pragma unroll
        for (int i = 0; i < 8; ++i) rv[i] = ald2(&hbuf[(((i << 9) + tid) << 1)]);
        #pragma unroll
        for (int i = 0; i < 8; ++i) ls2[(i << 9) + tid] = rv[i];
      }
      __syncthreads();
      // stage 1: bb_j = lecun_tanh(pre + h . Whh[j])
      float a1[8];
      #pragma unroll
      for (int b = 0; b < 8; ++b) a1[b] = 0.f;
      #pragma unroll
      for (int c = 0; c < 4; ++c) {
        int idx = (c << 6) + lane;
        float4 w = wreg[c];
        #pragma unroll
        for (int b = 0; b < 8; ++b) {
          float4 hv = ls4[(b << 8) + idx];
          a1[b] += w.x * hv.x + w.y * hv.y + w.z * hv.z + w.w * hv.w;
        }
      }
      #pragma unroll
      for (int m = 1; m < 64; m <<= 1)
        #pragma unroll
        for (int b = 0; b < 8; ++b) a1[b] += __shfl_xor(a1[b], m);
      if (lane == 0) {
        int tq = t & 63;
        #pragma unroll
        for (int b = 0; b < 8; ++b) {
          float s = a1[b] + lpre[((b << 6) + tq) * 8 + wave];
          ast(&bbf[b * NBB + j1], 1.7159f * tanhf(0.666f * s));
        }
      }
      __syncthreads();                      // drains bb stores + h loads (vmcnt)
      if (wave == 0)                        // signal all 64 V consumers
        astu(doneJ + ((lane << 10) + (jb << 4)), (unsigned)(t + 1));
    }
  } else {
    // ================= V-block =================
    int vb = bx - 64;
    int head = lane >> 4, v2 = (lane >> 3) & 1, jsub = lane & 7;
    int vg = (vb << 4) + (wave << 1) + v2;  // this lane-group's v unit
    const float4* W24 = (const float4*)(WhT + ((long)head * NU + vg) * NBB);
    float4 w2reg[16];
    #pragma unroll
    for (int c = 0; c < 16; ++c) w2reg[c] = W24[(c << 3) + jsub];
    // tail mapping (tid < 128): 16 v x 8 batches
    int vl = tid >> 3, bq = tid & 7;
    int wv = vl >> 1, qq = vl & 1;
    int vo = (vb << 4) + vl;
    float cb1 = 0.f, cb2 = 0.f, cbt = 0.f;
    if (tid < 128) { cb1 = bf1[vo]; cb2 = bf2[vo]; cbt = bta[vo] + btb[vo]; }
    const unsigned* mycell = doneJ + ((vb << 10) + (lane << 4));

    // init h(0) slice, then signal doneV = 1
    if (tid < 128) ast(&hbuf[bq * NU + vo], hx[bq * NU + vo]);
    __syncthreads();
    if (wave == 0)
      astu(doneV + ((lane << 10) + (vb << 4)), 1u);

    for (int t = 0; t < NS; ++t) {
      // wait: bb(t) ready (64 private cells, one per producer J-block)
      if (wave == 0) {
        while (aldu(mycell) < (unsigned)(t + 1)) {}
      }
      __syncthreads();
      // stage bb(t): 16KB via 8B sc loads (512 thr x 4)
      {
        float2 rv[4];
        #pragma unroll
        for (int i = 0; i < 4; ++i) rv[i] = ald2(&bbf[(((i << 9) + tid) << 1)]);
        #pragma unroll
        for (int i = 0; i < 4; ++i) ls2[(i << 9) + tid] = rv[i];
      }
      __syncthreads();
      // stage 2: head dots over bb
      float a2[8];
      #pragma unroll
      for (int b = 0; b < 8; ++b) a2[b] = 0.f;
      #pragma unroll
      for (int c = 0; c < 16; ++c) {
        int idx = (c << 3) + jsub;
        float4 w = w2reg[c];
        #pragma unroll
        for (int b = 0; b < 8; ++b) {
          float4 bv = ls4[(b << 7) + idx];
          a2[b] += w.x * bv.x + w.y * bv.y + w.z * bv.z + w.w * bv.w;
        }
      }
      #pragma unroll
      for (int m = 1; m < 8; m <<= 1)
        #pragma unroll
        for (int b = 0; b < 8; ++b) a2[b] += __shfl_xor(a2[b], m);
      if (jsub == 0) {
        #pragma unroll
        for (int b = 0; b < 8; ++b) lpart[wave][head][v2][b] = a2[b];
      }
      __syncthreads();
      float hn = 0.f;
      if (tid < 128) {
        float d1 = lpart[wv][0][qq][bq] + cb1;
        float d2 = lpart[wv][1][qq][bq] + cb2;
        float dt = lpart[wv][2][qq][bq] + lpart[wv][3][qq][bq] + cbt;
        float f1 = 1.7159f * tanhf(0.666f * d1);
        float f2 = 1.7159f * tanhf(0.666f * d2);
        float ti = 1.f / (1.f + expf(-dt));
        hn = f1 * (1.f - ti) + ti * f2;
        ast(&hbuf[bq * NU + vo], hn);       // h(t+1), sc store
      }
      __syncthreads();                      // drains h stores + bb loads (vmcnt)
      if (wave == 0)                        // signal all 64 J consumers
        astu(doneV + ((lane << 10) + (vb << 4)), (unsigned)(t + 2));
      // cfc store off the critical path (normal store; flushed at kernel end)
      if (tid < 128 && vo < NE) cfc[((long)bq * NS + t) * NE + vo] = hn;
    }
  }
}

// ---------------- LIF gate + residual (writes x1 into d_out), copy hx ----------------
__global__ __launch_bounds__(256) void lif_kernel(
    const float* __restrict__ x, const float* __restrict__ cfc,
    const float* __restrict__ thr, const float* __restrict__ leak,
    const float* __restrict__ steep, const float* __restrict__ hbuf,
    float* __restrict__ x1, float* __restrict__ outTail)
{
  long i4 = (long)blockIdx.x * blockDim.x + threadIdx.x;  // float4 index
  float4 xv = ((const float4*)x)[i4];
  float4 cv = ((const float4*)cfc)[i4];
  int col = (int)((i4 << 2) % NE);
  float4 tv = *(const float4*)(thr + col);
  float4 lv = *(const float4*)(leak + col);
  float4 sv = *(const float4*)(steep + col);
  float4 r;
#define LIF1(comp) { \
    float th = fabsf(tv.comp) * 0.1f; \
    float ls = 1.f / (1.f + expf(-lv.comp)); \
    float sp = (sv.comp > 20.f) ? sv.comp : log1pf(expf(sv.comp)); \
    float fire = 1.f / (1.f + expf(-sp * (fabsf(cv.comp) - th))); \
    float gate = fire + ls * (1.f - fire); \
    r.comp = xv.comp + cv.comp * gate; }
  LIF1(x) LIF1(y) LIF1(z) LIF1(w)
#undef LIF1
  ((float4*)x1)[i4] = r;
  if (i4 < (NB * NU / 4)) {
    // hbuf was written with sc stores; read it back with sc loads
    const float* hp = hbuf + (i4 << 2);
    float4 hv; hv.x = ald(hp); hv.y = ald(hp + 1); hv.z = ald(hp + 2); hv.w = ald(hp + 3);
    ((float4*)outTail)[i4] = hv;
  }
}

// ---------------- launch ----------------
extern "C" void kernel_launch(void* const* d_in, const int* in_sizes, int n_in,
                              void* d_out, int out_size, void* d_ws, size_t ws_size,
                              hipStream_t stream) {
  (void)in_sizes; (void)n_in; (void)out_size; (void)ws_size;
  const float* x     = (const float*)d_in[0];
  const float* hx    = (const float*)d_in[1];
  const float* ln1g  = (const float*)d_in[2];
  const float* ln1b  = (const float*)d_in[3];
  const float* ln2g  = (const float*)d_in[4];
  const float* ln2b  = (const float*)d_in[5];
  const float* Wbb   = (const float*)d_in[6];
  const float* bbb   = (const float*)d_in[7];
  const float* Wff1  = (const float*)d_in[8];
  const float* bff1  = (const float*)d_in[9];
  const float* Wff2  = (const float*)d_in[10];
  const float* bff2  = (const float*)d_in[11];
  const float* Wta   = (const float*)d_in[12];
  const float* btaP  = (const float*)d_in[13];
  const float* Wtb   = (const float*)d_in[14];
  const float* btbP  = (const float*)d_in[15];
  const float* lthr  = (const float*)d_in[16];
  const float* lleak = (const float*)d_in[17];
  const float* lstp  = (const float*)d_in[18];
  const float* W1    = (const float*)d_in[19];
  const float* b1    = (const float*)d_in[20];
  const float* W2    = (const float*)d_in[21];
  const float* b2    = (const float*)d_in[22];

  char* base = (char*)d_ws;
  unsigned short* normedH = (unsigned short*)base;                   // [0, 25165824)
  float* pre   = (float*)(base + 25165824);                          // [25165824, 58720256)
  float* cfc   = (float*)(base + 58720256);                          // [58720256, 109051904)
  unsigned short* gelu = (unsigned short*)base;                      // [0, 100663296) after cfc consumed
  unsigned short* normedL = (unsigned short*)(base + 109051904);     // [109051904, 134217728)
  unsigned short* h2      = (unsigned short*)(base + 109051904);     // same slot, later phase
  // done matrices: 512KB inside the normedL/h2 slot (dead during the scan;
  // h2 is written only after the scan completes)
  unsigned* doneV = (unsigned*)(base + 125829120);                   // 262144 B
  unsigned* doneJ = (unsigned*)(base + 126091264);                   // 262144 B
  unsigned short* wtbbH = (unsigned short*)(base + 134217728);       // 786432
  float* whhT  = (float*)(base + 135004160);                         // 2097152
  float* whT   = (float*)(base + 137101312);                         // 8388608
  unsigned short* w1t = (unsigned short*)(base + 145489920);         // 4718592
  unsigned short* w2t = (unsigned short*)(base + 150208512);         // 4718592
  float* hbuf  = (float*)(base + 154927104);                         // 32768
  float* bbf   = (float*)(base + 154959872);                         // 16384
  unsigned short* wtbbL = (unsigned short*)(base + 154980352);       // 786432 -> end 155766784
  float* xout  = (float*)d_out;
  float* outTail = xout + (size_t)NBS * NE;
  unsigned short* lnlo_dummy = (unsigned short*)base;                // scratch, overwritten by gelu

  dim3 b328(32, 8);
  // weight prep (transposed, K-contiguous layouts)
  tr_f32_bf16split<<<dim3(512/32, 768/32), b328, 0, stream>>>(Wbb, wtbbH, wtbbL, 768, 512);
  tr_f32<<<dim3(512/32, 1024/32), b328, 0, stream>>>(Wbb + 768*512, whhT, 1024, 512);
  tr_f32<<<dim3(1024/32, 512/32), b328, 0, stream>>>(Wff1, whT + 0*(size_t)NU*NBB, 512, 1024);
  tr_f32<<<dim3(1024/32, 512/32), b328, 0, stream>>>(Wff2, whT + 1*(size_t)NU*NBB, 512, 1024);
  tr_f32<<<dim3(1024/32, 512/32), b328, 0, stream>>>(Wta,  whT + 2*(size_t)NU*NBB, 512, 1024);
  tr_f32<<<dim3(1024/32, 512/32), b328, 0, stream>>>(Wtb,  whT + 3*(size_t)NU*NBB, 512, 1024);
  tr_f32_bf16<<<dim3(3072/32, 768/32), b328, 0, stream>>>(W1, w1t, 768, 3072);
  tr_f32_bf16<<<dim3(768/32, 3072/32), b328, 0, stream>>>(W2, w2t, 3072, 768);

  // LN1 (hi/lo split) + input-projection precompute in ~fp32 precision:
  // pre = nH@wH + nH@wL + nL@wH + b_bb
  ln_kernel<<<NBS/4, 256, 0, stream>>>(x, ln1g, ln1b, normedH, normedL);
  gemm_bf16<0><<<(NBS/128)*(NBB/128), 256, 0, stream>>>(normedH, wtbbH, bbb, nullptr,
                                                        pre, nullptr, NBS, NBB, NE);
  gemm_bf16<3><<<(NBS/128)*(NBB/128), 256, 0, stream>>>(normedH, wtbbL, bbb, nullptr,
                                                        pre, nullptr, NBS, NBB, NE);
  gemm_bf16<3><<<(NBS/128)*(NBB/128), 256, 0, stream>>>(normedL, wtbbH, bbb, nullptr,
                                                        pre, nullptr, NBS, NBB, NE);

  // zero the done matrices (stream-ordered after the pre-GEMMs that read
  // normedL, which this region aliases)
  hipMemsetAsync(doneV, 0, 524288, stream);

  scan_kernel<<<128, 512, 0, stream>>>(pre, whhT, whT, bff1, bff2, btaP, btbP, hx,
                                       hbuf, bbf, cfc, doneV, doneJ);

  // LIF gate + residual -> x1 (stored in d_out), plus new_hx copy to output tail
  lif_kernel<<<(NBS*NE/4)/256, 256, 0, stream>>>(x, cfc, lthr, lleak, lstp, hbuf, xout, outTail);
  // LN2 + MLP with fused GELU and residual
  ln_kernel<<<NBS/4, 256, 0, stream>>>(xout, ln2g, ln2b, h2, lnlo_dummy);
  gemm_bf16<1><<<(NBS/128)*(NH/128), 256, 0, stream>>>(h2, w1t, b1, nullptr,
                                                       nullptr, gelu, NBS, NH, NE);
  gemm_bf16<2><<<(NBS/128)*(NE/128), 256, 0, stream>>>(gelu, w2t, b2, xout,
                                                       xout, nullptr, NBS, NE, NH);
}

// Round 13
// 17281.514 us; speedup vs baseline: 2.1681x; 1.0844x over previous
//
#include <hip/hip_runtime.h>
#include <math.h>

#define NB 8
#define NS 2048
#define NE 768
#define NU 1024
#define NBB 512
#define NH 3072
#define NBS (NB*NS)   // 16384

typedef float f32x4v __attribute__((ext_vector_type(4)));
typedef __bf16 bf16x8v __attribute__((ext_vector_type(8)));
typedef unsigned short u16x8v __attribute__((ext_vector_type(8)));
typedef unsigned short u16x4v __attribute__((ext_vector_type(4)));

__device__ __forceinline__ unsigned short f2bf(float f) {
  unsigned int u = __builtin_bit_cast(unsigned int, f);
  u = (u + 0x7fffu + ((u >> 16) & 1u)) >> 16;
  return (unsigned short)u;
}
__device__ __forceinline__ float bf2f(unsigned short h) {
  unsigned int u = ((unsigned int)h) << 16;
  return __builtin_bit_cast(float, u);
}

// agent-scope (device) relaxed ops: sc0 sc1 loads/stores, coherent at LLC.
__device__ __forceinline__ float ald(const float* p) {
  return __hip_atomic_load((const float*)p, __ATOMIC_RELAXED, __HIP_MEMORY_SCOPE_AGENT);
}
__device__ __forceinline__ void ast(float* p, float v) {
  __hip_atomic_store(p, v, __ATOMIC_RELAXED, __HIP_MEMORY_SCOPE_AGENT);
}
__device__ __forceinline__ unsigned aldu(const unsigned* p) {
  return __hip_atomic_load(p, __ATOMIC_RELAXED, __HIP_MEMORY_SCOPE_AGENT);
}
__device__ __forceinline__ void astu(unsigned* p, unsigned v) {
  __hip_atomic_store(p, v, __ATOMIC_RELAXED, __HIP_MEMORY_SCOPE_AGENT);
}
// 16B LLC-coherent load (sc0 sc1): 4x fewer LLC requests than 8B atomic
// loads. Caller MUST execute wait_vmcnt0() before using the result.
__device__ __forceinline__ float4 ald4(const float* p) {
  float4 v;
  asm volatile("global_load_dwordx4 %0, %1, off sc0 sc1"
               : "=v"(v) : "v"(p) : "memory");
  return v;
}
__device__ __forceinline__ void wait_vmcnt0() {
  asm volatile("s_waitcnt vmcnt(0)" ::: "memory");
  __builtin_amdgcn_sched_barrier(0);
}

// ---------------- transpose kernels (weight prep) ----------------
__global__ __launch_bounds__(256) void tr_f32(const float* __restrict__ in,
                                              float* __restrict__ out, int R, int C) {
  __shared__ float tile[32][33];
  int c0 = blockIdx.x * 32, r0 = blockIdx.y * 32;
  int tx = threadIdx.x, ty = threadIdx.y;  // block (32,8)
  #pragma unroll
  for (int i = 0; i < 32; i += 8)
    tile[ty + i][tx] = in[(long)(r0 + ty + i) * C + c0 + tx];
  __syncthreads();
  #pragma unroll
  for (int i = 0; i < 32; i += 8)
    out[(long)(c0 + ty + i) * R + r0 + tx] = tile[tx][ty + i];
}

__global__ __launch_bounds__(256) void tr_f32_bf16(const float* __restrict__ in,
                                                   unsigned short* __restrict__ out, int R, int C) {
  __shared__ float tile[32][33];
  int c0 = blockIdx.x * 32, r0 = blockIdx.y * 32;
  int tx = threadIdx.x, ty = threadIdx.y;
  #pragma unroll
  for (int i = 0; i < 32; i += 8)
    tile[ty + i][tx] = in[(long)(r0 + ty + i) * C + c0 + tx];
  __syncthreads();
  #pragma unroll
  for (int i = 0; i < 32; i += 8)
    out[(long)(c0 + ty + i) * R + r0 + tx] = f2bf(tile[tx][ty + i]);
}

// transpose + split into bf16 hi/lo pair (for ~fp32-precision GEMM)
__global__ __launch_bounds__(256) void tr_f32_bf16split(const float* __restrict__ in,
    unsigned short* __restrict__ oh, unsigned short* __restrict__ ol, int R, int C) {
  __shared__ float tile[32][33];
  int c0 = blockIdx.x * 32, r0 = blockIdx.y * 32;
  int tx = threadIdx.x, ty = threadIdx.y;
  #pragma unroll
  for (int i = 0; i < 32; i += 8)
    tile[ty + i][tx] = in[(long)(r0 + ty + i) * C + c0 + tx];
  __syncthreads();
  #pragma unroll
  for (int i = 0; i < 32; i += 8) {
    float v = tile[tx][ty + i];
    unsigned short h = f2bf(v);
    long idx = (long)(c0 + ty + i) * R + r0 + tx;
    oh[idx] = h;
    ol[idx] = f2bf(v - bf2f(h));
  }
}

// ---------------- LayerNorm (one wave per row of 768) -> bf16 hi/lo out ----------------
__global__ __launch_bounds__(256) void ln_kernel(const float* __restrict__ in,
    const float* __restrict__ gw, const float* __restrict__ bw,
    unsigned short* __restrict__ outh, unsigned short* __restrict__ outl) {
  int lane = threadIdx.x & 63;
  long row = (long)blockIdx.x * 4 + (threadIdx.x >> 6);
  const float4* rp = (const float4*)(in + row * NE);
  float4 v[3];
  float s = 0.f, sq = 0.f;
  #pragma unroll
  for (int j = 0; j < 3; ++j) {
    v[j] = rp[lane + j * 64];
    s += v[j].x + v[j].y + v[j].z + v[j].w;
    sq += v[j].x*v[j].x + v[j].y*v[j].y + v[j].z*v[j].z + v[j].w*v[j].w;
  }
  #pragma unroll
  for (int m = 1; m < 64; m <<= 1) { s += __shfl_xor(s, m); sq += __shfl_xor(sq, m); }
  float mu = s * (1.f / NE);
  float rs = rsqrtf(sq * (1.f / NE) - mu * mu + 1e-5f);
  #pragma unroll
  for (int j = 0; j < 3; ++j) {
    int c4 = lane + j * 64;
    float4 g4 = ((const float4*)gw)[c4];
    float4 b4 = ((const float4*)bw)[c4];
    float f0 = (v[j].x - mu) * rs * g4.x + b4.x;
    float f1 = (v[j].y - mu) * rs * g4.y + b4.y;
    float f2 = (v[j].z - mu) * rs * g4.z + b4.z;
    float f3 = (v[j].w - mu) * rs * g4.w + b4.w;
    u16x4v oh, ol;
    oh[0] = f2bf(f0); ol[0] = f2bf(f0 - bf2f(oh[0]));
    oh[1] = f2bf(f1); ol[1] = f2bf(f1 - bf2f(oh[1]));
    oh[2] = f2bf(f2); ol[2] = f2bf(f2 - bf2f(oh[2]));
    oh[3] = f2bf(f3); ol[3] = f2bf(f3 - bf2f(oh[3]));
    *(u16x4v*)(outh + row * NE + (long)c4 * 4) = oh;
    *(u16x4v*)(outl + row * NE + (long)c4 * 4) = ol;
  }
}

// ---------------- bf16 MFMA GEMM: C[M,N] = A[M,K] @ Bt[N,K]^T (+bias, epilogue) ---
// EPI 0: Cf = acc + bias            (fp32 out)
// EPI 1: Cb = bf16(gelu(acc+bias))  (bf16 out)
// EPI 2: Cf = acc + bias + res      (fp32 out, residual add; res may alias Cf)
// EPI 3: Cf += acc                  (fp32 accumulate, no bias)
template<int EPI>
__global__ __launch_bounds__(256) void gemm_bf16(
    const unsigned short* __restrict__ A, const unsigned short* __restrict__ Bt,
    const float* __restrict__ bias, const float* res,
    float* Cf, unsigned short* Cb, int M, int N, int K)
{
  __shared__ unsigned short lA[128][72];
  __shared__ unsigned short lB[128][72];
  int tid = threadIdx.x;
  int lane = tid & 63, wave = tid >> 6;
  int wr = wave >> 1, wc = wave & 1;
  int r15 = lane & 15, hi = lane >> 4;
  int ntn = N >> 7;
  long m0 = (long)(blockIdx.x / ntn) << 7;
  long n0 = (long)(blockIdx.x % ntn) << 7;
  f32x4v acc[4][4];
  #pragma unroll
  for (int m = 0; m < 4; ++m)
    #pragma unroll
    for (int n = 0; n < 4; ++n) acc[m][n] = (f32x4v){0.f, 0.f, 0.f, 0.f};

  for (int kt = 0; kt < K; kt += 64) {
    u16x8v ra[4], rb[4];
    #pragma unroll
    for (int i = 0; i < 4; ++i) {
      int c = tid + (i << 8);
      int rw = c >> 3, ko = (c & 7) << 3;
      ra[i] = *(const u16x8v*)(A + (m0 + rw) * K + kt + ko);
      rb[i] = *(const u16x8v*)(Bt + (n0 + rw) * K + kt + ko);
    }
    __syncthreads();
    #pragma unroll
    for (int i = 0; i < 4; ++i) {
      int c = tid + (i << 8);
      int rw = c >> 3, ko = (c & 7) << 3;
      *(u16x8v*)(&lA[rw][ko]) = ra[i];
      *(u16x8v*)(&lB[rw][ko]) = rb[i];
    }
    __syncthreads();
    #pragma unroll
    for (int ks = 0; ks < 64; ks += 32) {
      bf16x8v af[4], bfr[4];
      #pragma unroll
      for (int m = 0; m < 4; ++m)
        af[m] = *(const bf16x8v*)(&lA[wr * 64 + m * 16 + r15][ks + hi * 8]);
      #pragma unroll
      for (int n = 0; n < 4; ++n)
        bfr[n] = *(const bf16x8v*)(&lB[wc * 64 + n * 16 + r15][ks + hi * 8]);
      #pragma unroll
      for (int m = 0; m < 4; ++m)
        #pragma unroll
        for (int n = 0; n < 4; ++n)
          acc[m][n] = __builtin_amdgcn_mfma_f32_16x16x32_bf16(af[m], bfr[n], acc[m][n], 0, 0, 0);
    }
  }
  #pragma unroll
  for (int m = 0; m < 4; ++m) {
    long rbase = m0 + wr * 64 + m * 16 + hi * 4;
    #pragma unroll
    for (int n = 0; n < 4; ++n) {
      long cg = n0 + wc * 64 + n * 16 + r15;
      float bs = (EPI == 3) ? 0.f : bias[cg];
      #pragma unroll
      for (int e = 0; e < 4; ++e) {
        long row = rbase + e;
        float vv = acc[m][n][e] + bs;
        if (EPI == 0) {
          Cf[row * N + cg] = vv;
        } else if (EPI == 1) {
          float gl = 0.5f * vv * (1.f + erff(vv * 0.70710678118f));
          Cb[row * N + cg] = f2bf(gl);
        } else if (EPI == 2) {
          Cf[row * N + cg] = vv + res[row * N + cg];
        } else {
          Cf[row * N + cg] += vv;
        }
      }
    }
  }
}

// ------------- persistent scan: PRODUCER/CONSUMER SPECIALIZED BLOCKS ----------
// grid = 128 x 512 threads, NO grid barrier. (r12 structure, proven.)
//   bx <  64: J-block jb — owns j = jb*8..+7. waits doneV(row jb) >= t+1,
//             stages h(t) (32KB, 16B sc loads), stage-1 dot, writes bb (sc),
//             signals doneJ[consumer][jb] = t+1 (64 private cells).
//   bx >= 64: V-block vb — owns v = vb*16..+15. waits doneJ(row vb) >= t+1,
//             stages bb(t) (16KB, 16B sc loads), stage-2 + h update, writes
//             h(t+1) (sc), signals doneV = t+2; cfc store off critical path.
// Staging uses global_load_dwordx4 sc0 sc1 (16B coherent loads): 4x fewer
// LLC requests than the r12 8B atomic loads — the ~6us/step request-service
// term this round removes. Explicit vmcnt(0)+sched_barrier before LDS use.
__global__ __launch_bounds__(512) void scan_kernel(
    const float* __restrict__ pre, const float* __restrict__ WhhT,
    const float* __restrict__ WhT,
    const float* __restrict__ bf1, const float* __restrict__ bf2,
    const float* __restrict__ bta, const float* __restrict__ btb,
    const float* __restrict__ hx,
    float* hbuf, float* bbf, float* __restrict__ cfc,
    unsigned* doneV, unsigned* doneJ)
{
  __shared__ float lsd[NB * NU];            // J: h image 32KB / V: bb image 16KB
  __shared__ float lpre[4096];              // J only: [b][t&63][8 j] = 16KB
  __shared__ float lpart[8][4][2][8];       // V only: 2KB
  int tid = threadIdx.x;
  int lane = tid & 63, wave = tid >> 6;     // 8 waves
  int bx = blockIdx.x;
  const float4* ls4 = (const float4*)lsd;
  float4* ls4w = (float4*)lsd;

  if (bx < 64) {
    // ================= J-block =================
    int jb = bx;
    int j1 = (jb << 3) + wave;              // this wave's j unit
    const float4* W14 = (const float4*)(WhhT + (long)j1 * NU);
    float4 wreg[4];
    #pragma unroll
    for (int c = 0; c < 4; ++c) wreg[c] = W14[(c << 6) + lane];
    const unsigned* mycell = doneV + ((jb << 10) + (lane << 4));

    for (int t = 0; t < NS; ++t) {
      // bulk pre reload every 64 steps (normal loads; in flight during poll)
      if ((t & 63) == 0) {
        int b = tid >> 6, tq = tid & 63;
        const float* src = pre + ((long)b * NS + t + tq) * NBB + (jb << 3);
        float4 p0 = *(const float4*)src;
        float4 p1 = *(const float4*)(src + 4);
        *(float4*)(&lpre[tid * 8])     = p0;
        *(float4*)(&lpre[tid * 8 + 4]) = p1;
      }
      // wait: h(t) ready (64 private cells, one per producer V-block)
      if (wave == 0) {
        while (aldu(mycell) < (unsigned)(t + 1)) {}
      }
      __syncthreads();
      // stage h(t): 32KB via 16B sc loads (512 thr x 4 float4)
      {
        float4 rv[4];
        #pragma unroll
        for (int i = 0; i < 4; ++i) rv[i] = ald4(&hbuf[(((i << 9) + tid) << 2)]);
        wait_vmcnt0();
        #pragma unroll
        for (int i = 0; i < 4; ++i) ls4w[(i << 9) + tid] = rv[i];
      }
      __syncthreads();
      // stage 1: bb_j = lecun_tanh(pre + h . Whh[j])
      float a1[8];
      #pragma unroll
      for (int b = 0; b < 8; ++b) a1[b] = 0.f;
      #pragma unroll
      for (int c = 0; c < 4; ++c) {
        int idx = (c << 6) + lane;
        float4 w = wreg[c];
        #pragma unroll
        for (int b = 0; b < 8; ++b) {
          float4 hv = ls4[(b << 8) + idx];
          a1[b] += w.x * hv.x + w.y * hv.y + w.z * hv.z + w.w * hv.w;
        }
      }
      #pragma unroll
      for (int m = 1; m < 64; m <<= 1)
        #pragma unroll
        for (int b = 0; b < 8; ++b) a1[b] += __shfl_xor(a1[b], m);
      // parallel tanh+store: lane b (0..7) handles batch b (all lanes hold
      // every a1[b] after the full butterfly)
      if (lane < 8) {
        int tq = t & 63;
        float s = a1[lane] + lpre[((lane << 6) + tq) * 8 + wave];
        ast(&bbf[lane * NBB + j1], 1.7159f * tanhf(0.666f * s));
      }
      __syncthreads();                      // drains bb stores + h loads (vmcnt)
      if (wave == 0)                        // signal all 64 V consumers
        astu(doneJ + ((lane << 10) + (jb << 4)), (unsigned)(t + 1));
    }
  } else {
    // ================= V-block =================
    int vb = bx - 64;
    int head = lane >> 4, v2 = (lane >> 3) & 1, jsub = lane & 7;
    int vg = (vb << 4) + (wave << 1) + v2;  // this lane-group's v unit
    const float4* W24 = (const float4*)(WhT + ((long)head * NU + vg) * NBB);
    float4 w2reg[16];
    #pragma unroll
    for (int c = 0; c < 16; ++c) w2reg[c] = W24[(c << 3) + jsub];
    // tail mapping (tid < 128): 16 v x 8 batches
    int vl = tid >> 3, bq = tid & 7;
    int wv = vl >> 1, qq = vl & 1;
    int vo = (vb << 4) + vl;
    float cb1 = 0.f, cb2 = 0.f, cbt = 0.f;
    if (tid < 128) { cb1 = bf1[vo]; cb2 = bf2[vo]; cbt = bta[vo] + btb[vo]; }
    const unsigned* mycell = doneJ + ((vb << 10) + (lane << 4));

    // init h(0) slice, then signal doneV = 1
    if (tid < 128) ast(&hbuf[bq * NU + vo], hx[bq * NU + vo]);
    __syncthreads();
    if (wave == 0)
      astu(doneV + ((lane << 10) + (vb << 4)), 1u);

    for (int t = 0; t < NS; ++t) {
      // wait: bb(t) ready (64 private cells, one per producer J-block)
      if (wave == 0) {
        while (aldu(mycell) < (unsigned)(t + 1)) {}
      }
      __syncthreads();
      // stage bb(t): 16KB via 16B sc loads (512 thr x 2 float4)
      {
        float4 rv[2];
        #pragma unroll
        for (int i = 0; i < 2; ++i) rv[i] = ald4(&bbf[(((i << 9) + tid) << 2)]);
        wait_vmcnt0();
        #pragma unroll
        for (int i = 0; i < 2; ++i) ls4w[(i << 9) + tid] = rv[i];
      }
      __syncthreads();
      // stage 2: head dots over bb
      float a2[8];
      #pragma unroll
      for (int b = 0; b < 8; ++b) a2[b] = 0.f;
      #pragma unroll
      for (int c = 0; c < 16; ++c) {
        int idx = (c << 3) + jsub;
        float4 w = w2reg[c];
        #pragma unroll
        for (int b = 0; b < 8; ++b) {
          float4 bv = ls4[(b << 7) + idx];
          a2[b] += w.x * bv.x + w.y * bv.y + w.z * bv.z + w.w * bv.w;
        }
      }
      #pragma unroll
      for (int m = 1; m < 8; m <<= 1)
        #pragma unroll
        for (int b = 0; b < 8; ++b) a2[b] += __shfl_xor(a2[b], m);
      if (jsub == 0) {
        #pragma unroll
        for (int b = 0; b < 8; ++b) lpart[wave][head][v2][b] = a2[b];
      }
      __syncthreads();
      float hn = 0.f;
      if (tid < 128) {
        float d1 = lpart[wv][0][qq][bq] + cb1;
        float d2 = lpart[wv][1][qq][bq] + cb2;
        float dt = lpart[wv][2][qq][bq] + lpart[wv][3][qq][bq] + cbt;
        float f1 = 1.7159f * tanhf(0.666f * d1);
        float f2 = 1.7159f * tanhf(0.666f * d2);
        float ti = 1.f / (1.f + expf(-dt));
        hn = f1 * (1.f - ti) + ti * f2;
        ast(&hbuf[bq * NU + vo], hn);       // h(t+1), sc store
      }
      __syncthreads();                      // drains h stores + bb loads (vmcnt)
      if (wave == 0)                        // signal all 64 J consumers
        astu(doneV + ((lane << 10) + (vb << 4)), (unsigned)(t + 2));
      // cfc store off the critical path (normal store; flushed at kernel end)
      if (tid < 128 && vo < NE) cfc[((long)bq * NS + t) * NE + vo] = hn;
    }
  }
}

// ---------------- LIF gate + residual (writes x1 into d_out), copy hx ----------------
__global__ __launch_bounds__(256) void lif_kernel(
    const float* __restrict__ x, const float* __restrict__ cfc,
    const float* __restrict__ thr, const float* __restrict__ leak,
    const float* __restrict__ steep, const float* __restrict__ hbuf,
    float* __restrict__ x1, float* __restrict__ outTail)
{
  long i4 = (long)blockIdx.x * blockDim.x + threadIdx.x;  // float4 index
  float4 xv = ((const float4*)x)[i4];
  float4 cv = ((const float4*)cfc)[i4];
  int col = (int)((i4 << 2) % NE);
  float4 tv = *(const float4*)(thr + col);
  float4 lv = *(const float4*)(leak + col);
  float4 sv = *(const float4*)(steep + col);
  float4 r;
#define LIF1(comp) { \
    float th = fabsf(tv.comp) * 0.1f; \
    float ls = 1.f / (1.f + expf(-lv.comp)); \
    float sp = (sv.comp > 20.f) ? sv.comp : log1pf(expf(sv.comp)); \
    float fire = 1.f / (1.f + expf(-sp * (fabsf(cv.comp) - th))); \
    float gate = fire + ls * (1.f - fire); \
    r.comp = xv.comp + cv.comp * gate; }
  LIF1(x) LIF1(y) LIF1(z) LIF1(w)
#undef LIF1
  ((float4*)x1)[i4] = r;
  if (i4 < (NB * NU / 4)) {
    // hbuf was written with sc stores; read it back with sc loads
    const float* hp = hbuf + (i4 << 2);
    float4 hv; hv.x = ald(hp); hv.y = ald(hp + 1); hv.z = ald(hp + 2); hv.w = ald(hp + 3);
    ((float4*)outTail)[i4] = hv;
  }
}

// ---------------- launch ----------------
extern "C" void kernel_launch(void* const* d_in, const int* in_sizes, int n_in,
                              void* d_out, int out_size, void* d_ws, size_t ws_size,
                              hipStream_t stream) {
  (void)in_sizes; (void)n_in; (void)out_size; (void)ws_size;
  const float* x     = (const float*)d_in[0];
  const float* hx    = (const float*)d_in[1];
  const float* ln1g  = (const float*)d_in[2];
  const float* ln1b  = (const float*)d_in[3];
  const float* ln2g  = (const float*)d_in[4];
  const float* ln2b  = (const float*)d_in[5];
  const float* Wbb   = (const float*)d_in[6];
  const float* bbb   = (const float*)d_in[7];
  const float* Wff1  = (const float*)d_in[8];
  const float* bff1  = (const float*)d_in[9];
  const float* Wff2  = (const float*)d_in[10];
  const float* bff2  = (const float*)d_in[11];
  const float* Wta   = (const float*)d_in[12];
  const float* btaP  = (const float*)d_in[13];
  const float* Wtb   = (const float*)d_in[14];
  const float* btbP  = (const float*)d_in[15];
  const float* lthr  = (const float*)d_in[16];
  const float* lleak = (const float*)d_in[17];
  const float* lstp  = (const float*)d_in[18];
  const float* W1    = (const float*)d_in[19];
  const float* b1    = (const float*)d_in[20];
  const float* W2    = (const float*)d_in[21];
  const float* b2    = (const float*)d_in[22];

  char* base = (char*)d_ws;
  unsigned short* normedH = (unsigned short*)base;                   // [0, 25165824)
  float* pre   = (float*)(base + 25165824);                          // [25165824, 58720256)
  float* cfc   = (float*)(base + 58720256);                          // [58720256, 109051904)
  unsigned short* gelu = (unsigned short*)base;                      // [0, 100663296) after cfc consumed
  unsigned short* normedL = (unsigned short*)(base + 109051904);     // [109051904, 134217728)
  unsigned short* h2      = (unsigned short*)(base + 109051904);     // same slot, later phase
  // done matrices: 512KB inside the normedL/h2 slot (dead during the scan;
  // h2 is written only after the scan completes)
  unsigned* doneV = (unsigned*)(base + 125829120);                   // 262144 B
  unsigned* doneJ = (unsigned*)(base + 126091264);                   // 262144 B
  unsigned short* wtbbH = (unsigned short*)(base + 134217728);       // 786432
  float* whhT  = (float*)(base + 135004160);                         // 2097152
  float* whT   = (float*)(base + 137101312);                         // 8388608
  unsigned short* w1t = (unsigned short*)(base + 145489920);         // 4718592
  unsigned short* w2t = (unsigned short*)(base + 150208512);         // 4718592
  float* hbuf  = (float*)(base + 154927104);                         // 32768
  float* bbf   = (float*)(base + 154959872);                         // 16384
  unsigned short* wtbbL = (unsigned short*)(base + 154980352);       // 786432 -> end 155766784
  float* xout  = (float*)d_out;
  float* outTail = xout + (size_t)NBS * NE;
  unsigned short* lnlo_dummy = (unsigned short*)base;                // scratch, overwritten by gelu

  dim3 b328(32, 8);
  // weight prep (transposed, K-contiguous layouts)
  tr_f32_bf16split<<<dim3(512/32, 768/32), b328, 0, stream>>>(Wbb, wtbbH, wtbbL, 768, 512);
  tr_f32<<<dim3(512/32, 1024/32), b328, 0, stream>>>(Wbb + 768*512, whhT, 1024, 512);
  tr_f32<<<dim3(1024/32, 512/32), b328, 0, stream>>>(Wff1, whT + 0*(size_t)NU*NBB, 512, 1024);
  tr_f32<<<dim3(1024/32, 512/32), b328, 0, stream>>>(Wff2, whT + 1*(size_t)NU*NBB, 512, 1024);
  tr_f32<<<dim3(1024/32, 512/32), b328, 0, stream>>>(Wta,  whT + 2*(size_t)NU*NBB, 512, 1024);
  tr_f32<<<dim3(1024/32, 512/32), b328, 0, stream>>>(Wtb,  whT + 3*(size_t)NU*NBB, 512, 1024);
  tr_f32_bf16<<<dim3(3072/32, 768/32), b328, 0, stream>>>(W1, w1t, 768, 3072);
  tr_f32_bf16<<<dim3(768/32, 3072/32), b328, 0, stream>>>(W2, w2t, 3072, 768);

  // LN1 (hi/lo split) + input-projection precompute in ~fp32 precision:
  // pre = nH@wH + nH@wL + nL@wH + b_bb
  ln_kernel<<<NBS/4, 256, 0, stream>>>(x, ln1g, ln1b, normedH, normedL);
  gemm_bf16<0><<<(NBS/128)*(NBB/128), 256, 0, stream>>>(normedH, wtbbH, bbb, nullptr,
                                                        pre, nullptr, NBS, NBB, NE);
  gemm_bf16<3><<<(NBS/128)*(NBB/128), 256, 0, stream>>>(normedH, wtbbL, bbb, nullptr,
                                                        pre, nullptr, NBS, NBB, NE);
  gemm_bf16<3><<<(NBS/128)*(NBB/128), 256, 0, stream>>>(normedL, wtbbH, bbb, nullptr,
                                                        pre, nullptr, NBS, NBB, NE);

  // zero the done matrices (stream-ordered after the pre-GEMMs that read
  // normedL, which this region aliases)
  hipMemsetAsync(doneV, 0, 524288, stream);

  scan_kernel<<<128, 512, 0, stream>>>(pre, whhT, whT, bff1, bff2, btaP, btbP, hx,
                                       hbuf, bbf, cfc, doneV, doneJ);

  // LIF gate + residual -> x1 (stored in d_out), plus new_hx copy to output tail
  lif_kernel<<<(NBS*NE/4)/256, 256, 0, stream>>>(x, cfc, lthr, lleak, lstp, hbuf, xout, outTail);
  // LN2 + MLP with fused GELU and residual
  ln_kernel<<<NBS/4, 256, 0, stream>>>(xout, ln2g, ln2b, h2, lnlo_dummy);
  gemm_bf16<1><<<(NBS/128)*(NH/128), 256, 0, stream>>>(h2, w1t, b1, nullptr,
                                                       nullptr, gelu, NBS, NH, NE);
  gemm_bf16<2><<<(NBS/128)*(NE/128), 256, 0, stream>>>(gelu, w2t, b2, xout,
                                                       xout, nullptr, NBS, NE, NH);
}